// Round 7
// baseline (168.966 us; speedup 1.0000x reference)
//
#include <hip/hip_runtime.h>

#define R_    512
#define K_    17
#define HIN   56
#define WIN   56
#define OUTS  96
#define NMAP  (R_ * K_)
#define NT    192
#define RST   98          // tmp row stride in v2f (196 dwords = 4 mod 32 -> staggered banks)
#define SROW  58          // stage row stride in floats (8B-aligned rows; 26 mod 32 -> 2-way free)
#define SMAP  (HIN * SROW)

typedef float v2f __attribute__((ext_vector_type(2)));

constexpr float cubic_c(float xin) {
    float x = xin < 0.0f ? -xin : xin;
    const float A = -0.75f;
    if (x <= 1.0f) return ((A + 2.0f) * x - (A + 3.0f)) * x * x + 1.0f;
    if (x < 2.0f)  return A * (((x - 5.0f) * x + 8.0f) * x - 4.0f);
    return 0.0f;
}

// X-pass: folded effective weights on contiguous window [s, s+3] (border clamp folded).
struct XTabT {
    float w[OUTS][4];
    int   s[OUTS];
    constexpr XTabT() : w{}, s{} {
        for (int o = 0; o < OUTS; ++o) {
            float src = ((float)o + 0.5f) * (56.0f / 96.0f) - 0.5f;
            int base = (int)src;
            if ((float)base > src) --base;
            int st = base - 1;
            if (st < 0) st = 0;
            if (st > HIN - 4) st = HIN - 4;
            s[o] = st;
            for (int q = 0; q < 4; ++q) {
                int tap = base - 1 + q;
                float wt = cubic_c(src - (float)tap);
                int p = tap < 0 ? 0 : (tap > HIN - 1 ? HIN - 1 : tap);
                w[o][p - st] += wt;
            }
        }
    }
};
constexpr XTabT XT;

// Y-pass: period-12 raw weights + relative tap start (tap0 logical row = 7*(h/12)+d[h%12]).
// Border handled by replicated pad rows in tmp (validated rounds 5/6: absmax 0.0).
struct YTabT {
    float w[12][4];
    int   d[12];
    constexpr YTabT() : w{}, d{} {
        for (int ph = 0; ph < 12; ++ph) {
            float src = ((float)ph + 0.5f) * (56.0f / 96.0f) - 0.5f;
            int base = (int)src;
            if ((float)base > src) --base;
            d[ph] = base - 1;
            for (int q = 0; q < 4; ++q)
                w[ph][q] = cubic_c(src - (float)(base - 1 + q));
        }
    }
};
constexpr YTabT YT;

// ---- phase 1: x-resize one row of BOTH maps (32 cols, group G) from LDS stage ----
template<int G>
__device__ __forceinline__ void p1_cols(const float* __restrict__ sa,
                                        const float* __restrict__ sb,
                                        v2f* __restrict__ dst) {
    constexpr int FS = (G == 0) ? 0 : (G == 1) ? 4 : 9;   // window start (float4 units)
    constexpr int NF = (G == 1) ? 6 : 5;
    v2f rr[NF * 4];
    {
        float a_[NF * 4], b_[NF * 4];
#pragma unroll
        for (int p = 0; p < NF * 2; ++p) {                // ds_read_b64, 2-way free
            float2 va = *(const float2*)(sa + 2 * p);
            float2 vb = *(const float2*)(sb + 2 * p);
            a_[2 * p] = va.x; a_[2 * p + 1] = va.y;
            b_[2 * p] = vb.x; b_[2 * p + 1] = vb.y;
        }
#pragma unroll
        for (int f = 0; f < NF * 4; ++f) rr[f] = (v2f){a_[f], b_[f]};
    }
#pragma unroll
    for (int i = 0; i < 16; ++i) {
        const int o0 = 32 * G + 2 * i, o1 = o0 + 1;
        const int s0 = XT.s[o0] - 4 * FS, s1 = XT.s[o1] - 4 * FS;
        v2f a0 = rr[s0] * (v2f){XT.w[o0][0], XT.w[o0][0]};
        a0 = __builtin_elementwise_fma((v2f){XT.w[o0][1], XT.w[o0][1]}, rr[s0 + 1], a0);
        a0 = __builtin_elementwise_fma((v2f){XT.w[o0][2], XT.w[o0][2]}, rr[s0 + 2], a0);
        a0 = __builtin_elementwise_fma((v2f){XT.w[o0][3], XT.w[o0][3]}, rr[s0 + 3], a0);
        v2f a1 = rr[s1] * (v2f){XT.w[o1][0], XT.w[o1][0]};
        a1 = __builtin_elementwise_fma((v2f){XT.w[o1][1], XT.w[o1][1]}, rr[s1 + 1], a1);
        a1 = __builtin_elementwise_fma((v2f){XT.w[o1][2], XT.w[o1][2]}, rr[s1 + 2], a1);
        a1 = __builtin_elementwise_fma((v2f){XT.w[o1][3], XT.w[o1][3]}, rr[s1 + 3], a1);
        *(float4*)(dst + 2 * i) = (float4){a0.x, a0.y, a1.x, a1.y};   // ds_write_b128
    }
}

// One tmp half: 32 phys rows. low: logical rows -2..29 ; high: logical 26..57.
__device__ __forceinline__ void p1_half(const float* __restrict__ stg,
                                        v2f* __restrict__ tmp, int t, bool low) {
    const int g = t >> 6;                 // wave-uniform col group
    const int w = t & 63;
    if (w >= 32) return;                  // 32 rows per half
    const int srcrow = low ? max(w - 2, 0) : min(26 + w, HIN - 1);
    const float* sa = stg + srcrow * SROW + ((g == 0) ? 0 : (g == 1) ? 16 : 36);
    const float* sb = sa + SMAP;
    v2f* dst = tmp + w * RST + 32 * g;
    if      (g == 0) p1_cols<0>(sa, sb, dst);
    else if (g == 1) p1_cols<1>(sa, sb, dst);
    else             p1_cols<2>(sa, sb, dst);
}

// ---- y-value: bit-identical chain shared by max-pass and rescan ----
__device__ __forceinline__ v2f yv(const v2f* __restrict__ c, int hh) {
    const int ph = hh % 12, b = hh / 12;
    const int i0 = 7 * b + YT.d[ph] + 2;            // in [0,14]; +3 <= 17
    v2f acc = c[i0] * (v2f){YT.w[ph][0], YT.w[ph][0]};
    acc = __builtin_elementwise_fma((v2f){YT.w[ph][1], YT.w[ph][1]}, c[i0 + 1], acc);
    acc = __builtin_elementwise_fma((v2f){YT.w[ph][2], YT.w[ph][2]}, c[i0 + 2], acc);
    acc = __builtin_elementwise_fma((v2f){YT.w[ph][3], YT.w[ph][3]}, c[i0 + 3], acc);
    return acc;
}

__global__ __launch_bounds__(NT, 3)
void _Keypointer_kernel(const float* __restrict__ masks,
                        const float* __restrict__ boxes,
                        float* __restrict__ out) {
    __shared__ __align__(16) float stg[2 * SMAP];   // 25984 B, persists whole kernel
    __shared__ __align__(16) v2f  tmp[32 * RST];    // 25088 B, ping-pong halves
    __shared__ v2f wmax[3];
    __shared__ int candp[2];

    const int t   = threadIdx.x;
    const int bm0 = 2 * blockIdx.x;

    // ---- stage both maps into LDS, fully coalesced dwordx4 ----
    {
        const float4* g4 = (const float4*)(masks + (size_t)bm0 * (HIN * WIN));
        int u = t, mm = 0, r = t / 14, kk = t % 14;
#pragma unroll
        for (int i = 0; i < 9; ++i) {
            if (i < 8 || u < 1568) {
                float4 v = g4[u];
                float* d = stg + mm * SMAP + r * SROW + 4 * kk;
                *(float2*)(d)     = make_float2(v.x, v.y);
                *(float2*)(d + 2) = make_float2(v.z, v.w);
            }
            u += NT;
            kk += 10; if (kk >= 14) { kk -= 14; ++r; }
            r += 13;  if (r >= HIN) { r -= HIN; mm = 1; }
        }
    }
    if (t == 0) { candp[0] = 0x7fffffff; candp[1] = 0x7fffffff; }
    __syncthreads();                                        // B1: stage ready

    // p2 thread mapping (uniform code, operand-only divergence)
    const int qq  = t / 96;                                 // row quarter within half
    const int col = t - 96 * qq;
    const v2f* cb = tmp + 14 * qq * RST + col;

    // ---- low half ----
    p1_half(stg, tmp, t, true);
    __syncthreads();                                        // B2: tmp(lo) ready
    v2f c_lo[18];
#pragma unroll
    for (int i = 0; i < 18; ++i) c_lo[i] = cb[i * RST];
    __syncthreads();                                        // B3: tmp(lo) consumed

    // ---- high half (overlaps with lo compute below via scheduler) ----
    p1_half(stg, tmp, t, false);

    v2f vmax = {-INFINITY, -INFINITY};
#pragma unroll
    for (int hh = 0; hh < 24; ++hh)
        vmax = __builtin_elementwise_max(vmax, yv(c_lo, hh));
    __syncthreads();                                        // B4: tmp(hi) ready

    v2f c_hi[18];
#pragma unroll
    for (int i = 0; i < 18; ++i) c_hi[i] = cb[i * RST];
#pragma unroll
    for (int hh = 0; hh < 24; ++hh)
        vmax = __builtin_elementwise_max(vmax, yv(c_hi, hh));

    // ---- block max per map ----
    float m0 = vmax.x, m1 = vmax.y;
#pragma unroll
    for (int off = 32; off > 0; off >>= 1) {
        m0 = fmaxf(m0, __shfl_down(m0, off, 64));
        m1 = fmaxf(m1, __shfl_down(m1, off, 64));
    }
    if ((t & 63) == 0) wmax[t >> 6] = (v2f){m0, m1};
    __syncthreads();                                        // B5

    const float M0 = fmaxf(fmaxf(wmax[0].x, wmax[1].x), wmax[2].x);
    const float M1 = fmaxf(fmaxf(wmax[0].y, wmax[1].y), wmax[2].y);

    // ---- sparse rescan (bit-identical recompute), first-occurrence argmax ----
    if (vmax.x == M0 || vmax.y == M1) {
        int c0 = 0x7fffffff, c1 = 0x7fffffff;
#pragma unroll
        for (int hh = 0; hh < 24; ++hh) {
            v2f a = yv(c_lo, hh);
            int fp = (24 * qq + hh) * OUTS + col;
            if (a.x == M0) c0 = min(c0, fp);
            if (a.y == M1) c1 = min(c1, fp);
        }
#pragma unroll
        for (int hh = 0; hh < 24; ++hh) {
            v2f a = yv(c_hi, hh);
            int fp = (48 + 24 * qq + hh) * OUTS + col;
            if (a.x == M0) c0 = min(c0, fp);
            if (a.y == M1) c1 = min(c1, fp);
        }
        if (c0 != 0x7fffffff) atomicMin(&candp[0], c0);
        if (c1 != 0x7fffffff) atomicMin(&candp[1], c1);
    }
    __syncthreads();                                        // B6

    if (t < 2) {
        const int map = bm0 + t;
        const float M = t ? M1 : M0;
        const int bp  = candp[t];
        const int r = map / K_, k = map - r * K_;
        const int y = bp / OUTS, x = bp - y * OUTS;
        const float b0f = boxes[r * 4 + 0], b1f = boxes[r * 4 + 1];
        const float b2f = boxes[r * 4 + 2], b3f = boxes[r * 4 + 3];
        const float corr0 = fmaxf(b2f - b0f, 1.0f) / (float)OUTS;
        const float corr1 = fmaxf(b3f - b1f, 1.0f) / (float)OUTS;
        const float p0 = ((float)y + 0.5f) * corr0 + b0f;
        const float p1 = ((float)x + 0.5f) * corr1 + b1f;
        out[(r * 3 + 0) * K_ + k] = p0;
        out[(r * 3 + 1) * K_ + k] = p1;
        out[(r * 3 + 2) * K_ + k] = 1.0f;
        out[R_ * 3 * K_ + r * K_ + k] = M;
    }
}

extern "C" void kernel_launch(void* const* d_in, const int* in_sizes, int n_in,
                              void* d_out, int out_size, void* d_ws, size_t ws_size,
                              hipStream_t stream) {
    const float* masks = (const float*)d_in[0];
    const float* boxes = (const float*)d_in[1];
    float* out = (float*)d_out;
    _Keypointer_kernel<<<NMAP / 2, NT, 0, stream>>>(masks, boxes, out);
}